// Round 4
// baseline (1129.465 us; speedup 1.0000x reference)
//
#include <hip/hip_runtime.h>

#define BLOCK 256
#define IC    64           // staged points per chunk
#define RPT   4            // rows per thread
#define ROWS  (BLOCK*RPT)  // 1024 rows per block

__device__ __forceinline__ float wave_reduce_add(float v) {
#pragma unroll
    for (int off = 32; off > 0; off >>= 1) v += __shfl_down(v, off, 64);
    return v;
}
__device__ __forceinline__ float lg2(float x) { return __builtin_amdgcn_logf(x); }
__device__ __forceinline__ float ex2(float x) { return __builtin_amdgcn_exp2f(x); }

__device__ __forceinline__ void load_rows(const float* p, float* x, float* y, float* z) {
    float4 v0 = *(const float4*)p;
    float4 v1 = *(const float4*)(p + 4);
    float4 v2 = *(const float4*)(p + 8);
    x[0]=v0.x; x[1]=v0.w; x[2]=v1.z; x[3]=v2.y;
    y[0]=v0.y; y[1]=v1.x; y[2]=v1.w; y[3]=v2.z;
    z[0]=v0.z; z[1]=v1.y; z[2]=v2.x; z[3]=v2.w;
}

__global__ __launch_bounds__(BLOCK)
void emd_init(float* __restrict__ satl, float* __restrict__ satr,
              float* __restrict__ out, float fl, float fr,
              int b, int n, int m) {
    int idx = blockIdx.x * blockDim.x + threadIdx.x;
    if (idx < b * n) satl[idx] = fl;
    if (idx < b * m) satr[idx] = fr;
    if (idx < b)     out[idx]  = 0.f;
}

// rowsum1 partials for level 0. P1p layout: [chunk][b*n] (coalesced both ways).
__global__ __launch_bounds__(BLOCK, 4)
void emd_pass1(const float* __restrict__ xyz1, const float* __restrict__ xyz2,
               const float* __restrict__ satr, float* __restrict__ P1p,
               float ls, int n, int m, int bn)
{
    __shared__ float4 sh[IC];
    const int bb = blockIdx.z, chunk = blockIdx.y;
    const float* x2 = xyz2 + (size_t)bb * m * 3;
    for (int t = threadIdx.x; t < IC; t += BLOCK) {
        int j = chunk * IC + t;
        sh[t] = make_float4(x2[3*j], x2[3*j+1], x2[3*j+2],
                            lg2(satr[(size_t)bb * m + j]));
    }
    __syncthreads();

    const int i0 = blockIdx.x * ROWS + threadIdx.x * RPT;
    float x[RPT], y[RPT], z[RPT], acc[RPT];
    load_rows(xyz1 + ((size_t)bb * n + i0) * 3, x, y, z);
#pragma unroll
    for (int r = 0; r < RPT; ++r) acc[r] = 0.f;
#pragma unroll 4
    for (int t = 0; t < IC; ++t) {
        float4 q = sh[t];
#pragma unroll
        for (int r = 0; r < RPT; ++r) {
            float dx = x[r] - q.x, dy = y[r] - q.y, dz = z[r] - q.z;
            float d2 = fmaf(dz, dz, fmaf(dy, dy, dx * dx));
            acc[r] += ex2(fmaf(d2, ls, q.w));
        }
    }
    *(float4*)&P1p[(size_t)chunk * bn + (size_t)bb * n + i0] =
        make_float4(acc[0], acc[1], acc[2], acc[3]);
}

// colsumE partials; staging computes a_i (and piggybacks satl update + cost of
// the previous level). P2p layout: [chunk][b*m].
__global__ __launch_bounds__(BLOCK, 4)
void emd_pass2(const float* __restrict__ xyz2, const float* __restrict__ xyz1,
               const float* __restrict__ satlPrev, float* __restrict__ satlNext,
               const float* __restrict__ aPrev, float* __restrict__ aOut,
               const float* __restrict__ P1p, const float* __restrict__ P3a,
               const float* __restrict__ P3b, float* __restrict__ P2p,
               float* __restrict__ cost,
               float ls, int n, int m, int C, int bn, int bm, int first)
{
    __shared__ float4 sh[IC];
    const int bb = blockIdx.z, chunk = blockIdx.y;
    const float* x1 = xyz1 + (size_t)bb * n * 3;
    for (int t = threadIdx.x; t < IC; t += BLOCK) {
        int i = chunk * IC + t;
        size_t ri = (size_t)bb * n + i;
        float rs = 0.f;
        for (int c = 0; c < C; ++c) rs += P1p[(size_t)c * bn + ri];
        float sl, costv = 0.f;
        if (first) {
            sl = satlPrev[ri];
        } else {
            float s1 = 0.f, s2 = 0.f;
            for (int c = 0; c < C; ++c) {
                s1 += P3a[(size_t)c * bn + ri];
                s2 += P3b[(size_t)c * bn + ri];
            }
            float ap = aPrev[ri];
            sl = fmaxf(satlPrev[ri] - ap * s1, 0.f);
            costv = ap * s2;
            if (blockIdx.x == 0) satlNext[ri] = sl;
        }
        float a = sl / (rs + 1e-9f);
        if (blockIdx.x == 0) aOut[ri] = a;
        sh[t] = make_float4(x1[3*i], x1[3*i+1], x1[3*i+2], lg2(a));
        if (!first && blockIdx.x == 0) {
            float cv = wave_reduce_add(costv);
            if ((threadIdx.x & 63) == 0) atomicAdd(&cost[bb], cv);
        }
    }
    __syncthreads();

    const int j0 = blockIdx.x * ROWS + threadIdx.x * RPT;
    float x[RPT], y[RPT], z[RPT], acc[RPT];
    load_rows(xyz2 + ((size_t)bb * m + j0) * 3, x, y, z);
#pragma unroll
    for (int r = 0; r < RPT; ++r) acc[r] = 0.f;
#pragma unroll 4
    for (int t = 0; t < IC; ++t) {
        float4 q = sh[t];
#pragma unroll
        for (int r = 0; r < RPT; ++r) {
            float dx = x[r] - q.x, dy = y[r] - q.y, dz = z[r] - q.z;
            float d2 = fmaf(dz, dz, fmaf(dy, dy, dx * dx));
            acc[r] += ex2(fmaf(d2, ls, q.w));
        }
    }
    *(float4*)&P2p[(size_t)chunk * bm + (size_t)bb * m + j0] =
        make_float4(acc[0], acc[1], acc[2], acc[3]);
}

// fused pass3(L) + pass1(L+1): one sweep, shared d2.
__global__ __launch_bounds__(BLOCK, 4)
void emd_fused(const float* __restrict__ xyz1, const float* __restrict__ xyz2,
               const float* __restrict__ satrCur, float* __restrict__ satrNext,
               const float* __restrict__ P2p,
               float* __restrict__ P3a, float* __restrict__ P3b,
               float* __restrict__ P1p,
               float lsA, float lsB, int n, int m, int C2, int bn, int bm)
{
    __shared__ float4 sh[IC];   // (qx,qy,qz, log2 r2)
    __shared__ float  shB[IC];  // log2 satr_next
    const int bb = blockIdx.z, chunk = blockIdx.y;
    const float* x2 = xyz2 + (size_t)bb * m * 3;
    for (int t = threadIdx.x; t < IC; t += BLOCK) {
        int j = chunk * IC + t;
        size_t rj = (size_t)bb * m + j;
        float cs = 0.f;
        for (int c = 0; c < C2; ++c) cs += P2p[(size_t)c * bm + rj];
        float sr  = satrCur[rj];
        float cs2 = sr * cs;
        float inv = sr / (cs2 + 1e-9f);
        float r2  = sr * inv;
        float sn  = fmaxf(sr - cs2 * inv, 0.f);
        if (blockIdx.x == 0) satrNext[rj] = sn;
        sh[t]  = make_float4(x2[3*j], x2[3*j+1], x2[3*j+2], lg2(r2));
        shB[t] = lg2(sn);
    }
    __syncthreads();

    const int i0 = blockIdx.x * ROWS + threadIdx.x * RPT;
    float x[RPT], y[RPT], z[RPT];
    load_rows(xyz1 + ((size_t)bb * n + i0) * 3, x, y, z);
    float s1[RPT], s2[RPT], r1[RPT];
#pragma unroll
    for (int r = 0; r < RPT; ++r) { s1[r] = 0.f; s2[r] = 0.f; r1[r] = 0.f; }
#pragma unroll 4
    for (int t = 0; t < IC; ++t) {
        float4 q = sh[t];
        float lb = shB[t];
#pragma unroll
        for (int r = 0; r < RPT; ++r) {
            float dx = x[r] - q.x, dy = y[r] - q.y, dz = z[r] - q.z;
            float d2 = fmaf(dz, dz, fmaf(dy, dy, dx * dx));
            float e3 = ex2(fmaf(d2, lsA, q.w));     // e * r2
            s1[r] += e3;
            float sq = __builtin_amdgcn_sqrtf(d2);
            s2[r] = fmaf(e3, sq, s2[r]);
            r1[r] += ex2(fmaf(d2, lsB, lb));        // next-level rowsum1 part
        }
    }
    size_t base = (size_t)chunk * bn + (size_t)bb * n + i0;
    *(float4*)&P3a[base] = make_float4(s1[0], s1[1], s1[2], s1[3]);
    *(float4*)&P3b[base] = make_float4(s2[0], s2[1], s2[2], s2[3]);
    *(float4*)&P1p[base] = make_float4(r1[0], r1[1], r1[2], r1[3]);
}

// Last level (level value = 0): exp term == 1 -> s2_i = sum_j r2_j * sqrt(d2).
__global__ __launch_bounds__(BLOCK, 4)
void emd_pass3_last(const float* __restrict__ xyz1, const float* __restrict__ xyz2,
                    const float* __restrict__ satrCur, const float* __restrict__ P2p,
                    float* __restrict__ P3b, int n, int m, int C2, int bn, int bm)
{
    __shared__ float4 sh[IC];   // (qx,qy,qz, r2)
    const int bb = blockIdx.z, chunk = blockIdx.y;
    const float* x2 = xyz2 + (size_t)bb * m * 3;
    for (int t = threadIdx.x; t < IC; t += BLOCK) {
        int j = chunk * IC + t;
        size_t rj = (size_t)bb * m + j;
        float cs = 0.f;
        for (int c = 0; c < C2; ++c) cs += P2p[(size_t)c * bm + rj];
        float sr  = satrCur[rj];
        float cs2 = sr * cs;
        float inv = sr / (cs2 + 1e-9f);
        sh[t] = make_float4(x2[3*j], x2[3*j+1], x2[3*j+2], sr * inv);
    }
    __syncthreads();

    const int i0 = blockIdx.x * ROWS + threadIdx.x * RPT;
    float x[RPT], y[RPT], z[RPT], s2[RPT];
    load_rows(xyz1 + ((size_t)bb * n + i0) * 3, x, y, z);
#pragma unroll
    for (int r = 0; r < RPT; ++r) s2[r] = 0.f;
#pragma unroll 4
    for (int t = 0; t < IC; ++t) {
        float4 q = sh[t];
#pragma unroll
        for (int r = 0; r < RPT; ++r) {
            float dx = x[r] - q.x, dy = y[r] - q.y, dz = z[r] - q.z;
            float d2 = fmaf(dz, dz, fmaf(dy, dy, dx * dx));
            s2[r] = fmaf(q.w, __builtin_amdgcn_sqrtf(d2), s2[r]);
        }
    }
    *(float4*)&P3b[(size_t)chunk * bn + (size_t)bb * n + i0] =
        make_float4(s2[0], s2[1], s2[2], s2[3]);
}

__global__ __launch_bounds__(BLOCK)
void emd_final(const float* __restrict__ a, const float* __restrict__ P3b,
               float* __restrict__ cost, int n, int C, int bn)
{
    const int bb = blockIdx.z;
    const int i  = blockIdx.x * BLOCK + threadIdx.x;
    size_t ri = (size_t)bb * n + i;
    float s2 = 0.f;
    for (int c = 0; c < C; ++c) s2 += P3b[(size_t)c * bn + ri];
    float cv = wave_reduce_add(a[ri] * s2);
    if ((threadIdx.x & 63) == 0) atomicAdd(&cost[bb], cv);
}

extern "C" void kernel_launch(void* const* d_in, const int* in_sizes, int n_in,
                              void* d_out, int out_size, void* d_ws, size_t ws_size,
                              hipStream_t stream)
{
    const float* xyz1 = (const float*)d_in[0];
    const float* xyz2 = (const float*)d_in[1];
    const int b = out_size;                 // 4
    const int n = in_sizes[0] / (3 * b);    // 4096
    const int m = in_sizes[1] / (3 * b);    // 4096
    const int C  = m / IC;                  // chunks over j
    const int C2 = n / IC;                  // chunks over i
    const int bn = b * n, bm = b * m;

    float* ws    = (float*)d_ws;
    float* satlA = ws; ws += (size_t)bn;
    float* satlB = ws; ws += (size_t)bn;
    float* satrA = ws; ws += (size_t)bm;
    float* satrB = ws; ws += (size_t)bm;
    float* aA    = ws; ws += (size_t)bn;
    float* aB    = ws; ws += (size_t)bn;
    float* P1p   = ws; ws += (size_t)bn * C;
    float* P2p   = ws; ws += (size_t)bm * C2;
    float* P3a   = ws; ws += (size_t)bn * C;
    float* P3b   = ws; ws += (size_t)bn * C;

    float* out = (float*)d_out;

    const int mx = n > m ? n : m;
    const float fl = (float)(mx / n), fr = (float)(mx / m);

    emd_init<<<dim3((b * mx + BLOCK - 1) / BLOCK), BLOCK, 0, stream>>>(
        satlA, satrA, out, fl, fr, b, n, m);

    const double LOG2E = 1.4426950408889634074;
    const double levels[11] = {-65536.0, -16384.0, -4096.0, -1024.0, -256.0,
                               -64.0, -16.0, -4.0, -1.0, -0.25, 0.0};
    float lsv[11];
    for (int k = 0; k < 11; ++k) lsv[k] = (float)(levels[k] * LOG2E);

    const dim3 g1(n / ROWS, m / IC, b);   // outer over xyz1 rows
    const dim3 g2(m / ROWS, n / IC, b);   // outer over xyz2 rows

    emd_pass1<<<g1, BLOCK, 0, stream>>>(xyz1, xyz2, satrA, P1p, lsv[0], n, m, bn);
    emd_pass2<<<g2, BLOCK, 0, stream>>>(xyz2, xyz1, satlA, satlB, aA, aA,
                                        P1p, P3a, P3b, P2p, out,
                                        lsv[0], n, m, C, bn, bm, 1);
    for (int L = 0; L < 10; ++L) {
        float* sc_ = (L % 2 == 0) ? satrA : satrB;
        float* sn_ = (L % 2 == 0) ? satrB : satrA;
        emd_fused<<<g1, BLOCK, 0, stream>>>(xyz1, xyz2, sc_, sn_, P2p,
                                            P3a, P3b, P1p,
                                            lsv[L], lsv[L + 1], n, m, C2, bn, bm);
        const int Lp = L + 1;
        float* slP = ((Lp + 1) % 2 == 0) ? satlA : satlB;
        float* slN = (Lp % 2 == 0)       ? satlA : satlB;
        float* aP  = ((Lp + 1) % 2 == 0) ? aA : aB;
        float* aO  = (Lp % 2 == 0)       ? aA : aB;
        emd_pass2<<<g2, BLOCK, 0, stream>>>(xyz2, xyz1, slP, slN, aP, aO,
                                            P1p, P3a, P3b, P2p, out,
                                            lsv[Lp], n, m, C, bn, bm, 0);
    }
    emd_pass3_last<<<g1, BLOCK, 0, stream>>>(xyz1, xyz2, satrA, P2p, P3b,
                                             n, m, C2, bn, bm);
    emd_final<<<dim3(n / BLOCK, 1, b), BLOCK, 0, stream>>>(aA, P3b, out, n, C, bn);
}